// Round 17
// baseline (16.517 us; speedup 1.0000x reference)
//
#include <hip/hip_runtime.h>

// Shapes (compile-time constants from the reference)
#define BQ 4     // B
#define VV 384   // V visible nodes
#define HH 128   // H hidden nodes
#define NN 512   // N = V + H
#define HDIM 64  // HD
#define TD 128   // T*D

typedef float f32x2 __attribute__((ext_vector_type(2)));

// Wave-uniform broadcast: readlane (VALU->SGPR, ~4cyc) instead of __shfl
// (ds_bpermute, ~60+cyc LDS-crossbar latency). Index must be wave-uniform.
__device__ __forceinline__ float BCAST(float v, int l) {
    return __int_as_float(__builtin_amdgcn_readlane(__float_as_int(v), l));
}
__device__ __forceinline__ f32x2 RELU2(f32x2 v) {
    f32x2 r; r.x = fmaxf(v.x, 0.f); r.y = fmaxf(v.y, 0.f); return r;
}

// ws layout (floats)
#define OFF_E2 0                    // B*V*64 = 98304
#define OFF_C1 (BQ * VV * HDIM)     // 64 floats: c1 = (relu(relu(b_e1)@w_e2+b_e2)) @ w_n1

// K1: R15 champion form (row-pair packed f32x2, 8 K-eighth waves, 768 blocks
// x 512 thr = 24 waves/CU, all co-resident). Block 0's o==1 wave additionally
// computes the constant c1 vector in the epilogue (off critical path).
__global__ __launch_bounds__(512) void k_rowpipe(
    const float* __restrict__ x,       // (B*V,128)
    const float* __restrict__ w_in1,   // (128,64)
    const float* __restrict__ b_in1,   // (64)
    const float* __restrict__ w_in2,   // (64,64)
    const float* __restrict__ b_in2,   // (64)
    const float* __restrict__ w_e1,    // (128,64) ; rows [64:128) = sender half
    const float* __restrict__ b_e1,    // (64)
    const float* __restrict__ w_e2,    // (64,64)
    const float* __restrict__ b_e2,    // (64)
    const float* __restrict__ w_n1,    // (64,64) — for c1
    float* __restrict__ E2,            // ws
    float* __restrict__ c1W)           // ws (64)
{
    __shared__ f32x2 part[4][8][HDIM];   // [layer][eighth][lane] = 16 KB

    const int o    = threadIdx.x >> 6;    // 0..7 : K-eighth
    const int lane = threadIdx.x & 63;
    const int row0 = blockIdx.x * 2;      // rows row0, row0+1 (flat b*V+j)

    const float* xr0 = x + (size_t)row0 * TD;
    const float* xr1 = xr0 + TD;
    // lanes 0-31 carry row0's 16 x-values (dup'd), 32-63 row1's
    const float xv = (lane < 32) ? xr0[16 * o + (lane & 15)]
                                 : xr1[16 * o + (lane & 15)];

    // layer in1: K=128, eighth kg in [16o, 16o+16)
    f32x2 a0 = {0.f, 0.f}, a1 = {0.f, 0.f};
    #pragma unroll
    for (int k = 0; k < 16; k += 2) {
        const int kg = 16 * o + k;
        f32x2 s0; s0.x = BCAST(xv, k);     s0.y = BCAST(xv, 32 + k);
        f32x2 s1; s1.x = BCAST(xv, k + 1); s1.y = BCAST(xv, 33 + k);
        a0 += s0 * w_in1[kg * HDIM + lane];
        a1 += s1 * w_in1[(kg + 1) * HDIM + lane];
    }
    part[0][o][lane] = a0 + a1;
    __syncthreads();
    f32x2 t = ((part[0][0][lane] + part[0][1][lane])
             + (part[0][2][lane] + part[0][3][lane]))
            + ((part[0][4][lane] + part[0][5][lane])
             + (part[0][6][lane] + part[0][7][lane]));
    const f32x2 h1 = RELU2(t + b_in1[lane]);
    const float h1x = h1.x, h1y = h1.y;

    // layer in2: K=64, eighth kg in [8o, 8o+8)
    a0 = (f32x2){0.f, 0.f}; a1 = (f32x2){0.f, 0.f};
    #pragma unroll
    for (int k = 0; k < 8; k += 2) {
        const int kg = 8 * o + k;
        f32x2 s0; s0.x = BCAST(h1x, kg);     s0.y = BCAST(h1y, kg);
        f32x2 s1; s1.x = BCAST(h1x, kg + 1); s1.y = BCAST(h1y, kg + 1);
        a0 += s0 * w_in2[kg * HDIM + lane];
        a1 += s1 * w_in2[(kg + 1) * HDIM + lane];
    }
    part[1][o][lane] = a0 + a1;
    __syncthreads();
    t = ((part[1][0][lane] + part[1][1][lane])
       + (part[1][2][lane] + part[1][3][lane]))
      + ((part[1][4][lane] + part[1][5][lane])
       + (part[1][6][lane] + part[1][7][lane]));
    const f32x2 h2 = RELU2(t + b_in2[lane]);
    const float h2x = h2.x, h2y = h2.y;

    // sender-side edge contribution: bb = h2 @ w_e1[HD:]
    a0 = (f32x2){0.f, 0.f}; a1 = (f32x2){0.f, 0.f};
    #pragma unroll
    for (int k = 0; k < 8; k += 2) {
        const int kg = 8 * o + k;
        f32x2 s0; s0.x = BCAST(h2x, kg);     s0.y = BCAST(h2y, kg);
        f32x2 s1; s1.x = BCAST(h2x, kg + 1); s1.y = BCAST(h2y, kg + 1);
        a0 += s0 * w_e1[(HDIM + kg) * HDIM + lane];
        a1 += s1 * w_e1[(HDIM + kg + 1) * HDIM + lane];
    }
    part[2][o][lane] = a0 + a1;
    __syncthreads();
    t = ((part[2][0][lane] + part[2][1][lane])
       + (part[2][2][lane] + part[2][3][lane]))
      + ((part[2][4][lane] + part[2][5][lane])
       + (part[2][6][lane] + part[2][7][lane]));
    const f32x2 e1 = RELU2(t + b_e1[lane]);
    const float e1x = e1.x, e1y = e1.y;

    // edge layer 2
    a0 = (f32x2){0.f, 0.f}; a1 = (f32x2){0.f, 0.f};
    #pragma unroll
    for (int k = 0; k < 8; k += 2) {
        const int kg = 8 * o + k;
        f32x2 s0; s0.x = BCAST(e1x, kg);     s0.y = BCAST(e1y, kg);
        f32x2 s1; s1.x = BCAST(e1x, kg + 1); s1.y = BCAST(e1y, kg + 1);
        a0 += s0 * w_e2[kg * HDIM + lane];
        a1 += s1 * w_e2[(kg + 1) * HDIM + lane];
    }
    part[3][o][lane] = a0 + a1;
    __syncthreads();
    if (o == 0) {
        t = ((part[3][0][lane] + part[3][1][lane])
           + (part[3][2][lane] + part[3][3][lane]))
          + ((part[3][4][lane] + part[3][5][lane])
           + (part[3][6][lane] + part[3][7][lane]));
        const f32x2 e2v = RELU2(t + b_e2[lane]);
        E2[(size_t)row0 * HDIM + lane]       = e2v.x;
        E2[(size_t)(row0 + 1) * HDIM + lane] = e2v.y;
    } else if (o == 1 && blockIdx.x == 0) {
        // constant c1 = relu(relu(b_e1)@w_e2 + b_e2) @ w_n1 (one wave, once)
        const float e1c = fmaxf(b_e1[lane], 0.f);
        float t0 = b_e2[lane], t1 = 0.f;
        #pragma unroll 8
        for (int k = 0; k < HDIM; k += 2) {
            t0 = fmaf(BCAST(e1c, k),     w_e2[k * HDIM + lane],       t0);
            t1 = fmaf(BCAST(e1c, k + 1), w_e2[(k + 1) * HDIM + lane], t1);
        }
        const float e2c = fmaxf(t0 + t1, 0.f);
        t0 = 0.f; t1 = 0.f;
        #pragma unroll 8
        for (int k = 0; k < HDIM; k += 2) {
            t0 = fmaf(BCAST(e2c, k),     w_n1[k * HDIM + lane],       t0);
            t1 = fmaf(BCAST(e2c, k + 1), w_n1[(k + 1) * HDIM + lane], t1);
        }
        c1W[lane] = t0 + t1;
    }
}

// K2: ONE hidden row per block; 512 blocks x 1024 thr = 2 blocks/CU,
// 32 waves/CU (hardware max). All 16 waves agg 24 visible j's; wave 15 also
// computes the hidden adj row-sum. hsum's E2-side folds into n1 via c1.
// Tail: waves 0-7 split K 8 ways (champion pattern); waves 8-15 idle at
// barriers (all waves stay live through every barrier).
__global__ __launch_bounds__(1024) void k_agg_out(
    const float* __restrict__ adj,   // (B,N,N)
    const float* __restrict__ E2,    // (B*V,64)
    const float* __restrict__ c1W,   // (64)
    const float* __restrict__ w_n1, const float* __restrict__ b_n1,
    const float* __restrict__ w_n2, const float* __restrict__ b_n2,
    const float* __restrict__ w_out, // (64,128)
    const float* __restrict__ b_out, // (128)
    float* __restrict__ out)         // (B,H,128)
{
    const int row  = blockIdx.x;          // 0..511 == b*H+hi
    const int b    = row >> 7;
    const int hi   = row & 127;
    const int i    = VV + hi;
    const int wid  = threadIdx.x >> 6;    // 0..15
    const int lane = threadIdx.x & 63;

    const float* adjrow = adj + ((size_t)b * NN + i) * NN;
    const int j0 = wid * 24;              // 16 waves x 24 j's = 384

    // coalesced load; only indices 0..23 are consumed via readlane
    const float adjv = adjrow[j0 + lane];

    __shared__ float redA[16][HDIM];      // 4 KB
    __shared__ float hsLDS;

    {
        const float* e2b = E2 + ((size_t)b * VV + j0) * HDIM;
        float p0 = 0.f, p1 = 0.f;
        #pragma unroll
        for (int jj = 0; jj < 24; jj += 2) {
            const float e0 = e2b[jj * HDIM + lane];
            const float e1 = e2b[(jj + 1) * HDIM + lane];
            p0 = fmaf(BCAST(adjv, jj),     e0, p0);
            p1 = fmaf(BCAST(adjv, jj + 1), e1, p1);
        }
        redA[wid][lane] = p0 + p1;
    }
    if (wid == 15) {
        // hidden-sender adj row-sum (senders j in [V, N))
        float s = adjrow[VV + lane] + adjrow[VV + 64 + lane];
        s += __shfl_xor(s, 32, 64);
        s += __shfl_xor(s, 16, 64);
        s += __shfl_xor(s, 8, 64);
        s += __shfl_xor(s, 4, 64);
        s += __shfl_xor(s, 2, 64);
        s += __shfl_xor(s, 1, 64);
        if (lane == 0) hsLDS = s;
    }
    __syncthreads();

    // visible agg (all tail waves redundantly reduce 16 parts)
    float agg = 0.f;
    #pragma unroll
    for (int w = 0; w < 16; ++w) agg += redA[w][lane];
    const float hsum = hsLDS;

    // layer n1: K split 8 ways across waves 0-7; hsum*c1 folded in post-reduce
    __shared__ float redB[8][HDIM];
    if (wid < 8) {
        float t0 = 0.f, t1 = 0.f;
        #pragma unroll
        for (int t = 0; t < 8; t += 2) {
            const int k = 8 * wid + t;
            t0 = fmaf(BCAST(agg, k),     w_n1[k * HDIM + lane],       t0);
            t1 = fmaf(BCAST(agg, k + 1), w_n1[(k + 1) * HDIM + lane], t1);
        }
        redB[wid][lane] = t0 + t1;
    }
    __syncthreads();
    float n1 = fmaf(hsum, c1W[lane], b_n1[lane]);
    #pragma unroll
    for (int w = 0; w < 8; ++w) n1 += redB[w][lane];
    n1 = fmaxf(n1, 0.f);

    // layer n2
    __shared__ float redC[8][HDIM];
    if (wid < 8) {
        float t0 = 0.f, t1 = 0.f;
        #pragma unroll
        for (int t = 0; t < 8; t += 2) {
            const int k = 8 * wid + t;
            t0 = fmaf(BCAST(n1, k),     w_n2[k * HDIM + lane],       t0);
            t1 = fmaf(BCAST(n1, k + 1), w_n2[(k + 1) * HDIM + lane], t1);
        }
        redC[wid][lane] = t0 + t1;
    }
    __syncthreads();
    float n2 = b_n2[lane];
    #pragma unroll
    for (int w = 0; w < 8; ++w) n2 += redC[w][lane];
    n2 = fmaxf(n2, 0.f);

    // out layer: 128 outputs, K split 8 ways over waves 0-7
    __shared__ float redD[8][TD];
    if (wid < 8) {
        float o0 = 0.f, o1 = 0.f;
        #pragma unroll
        for (int t = 0; t < 8; ++t) {
            const int k = 8 * wid + t;
            const float v = BCAST(n2, k);
            o0 = fmaf(v, w_out[k * TD + lane],      o0);
            o1 = fmaf(v, w_out[k * TD + 64 + lane], o1);
        }
        redD[wid][lane]      = o0;
        redD[wid][64 + lane] = o1;
    }
    __syncthreads();

    if (wid < 2) {
        const int col = wid * 64 + lane;
        float o = b_out[col];
        #pragma unroll
        for (int w = 0; w < 8; ++w) o += redD[w][col];
        out[(size_t)row * TD + col] = o;
    }
}

extern "C" void kernel_launch(void* const* d_in, const int* in_sizes, int n_in,
                              void* d_out, int out_size, void* d_ws, size_t ws_size,
                              hipStream_t stream) {
    const float* x     = (const float*)d_in[0];
    const float* adj   = (const float*)d_in[1];
    const float* w_in1 = (const float*)d_in[2];
    const float* b_in1 = (const float*)d_in[3];
    const float* w_in2 = (const float*)d_in[4];
    const float* b_in2 = (const float*)d_in[5];
    const float* w_e1  = (const float*)d_in[6];
    const float* b_e1  = (const float*)d_in[7];
    const float* w_e2  = (const float*)d_in[8];
    const float* b_e2  = (const float*)d_in[9];
    const float* w_n1  = (const float*)d_in[10];
    const float* b_n1  = (const float*)d_in[11];
    const float* w_n2  = (const float*)d_in[12];
    const float* b_n2  = (const float*)d_in[13];
    const float* w_out = (const float*)d_in[14];
    const float* b_out = (const float*)d_in[15];
    float* out  = (float*)d_out;
    float* ws   = (float*)d_ws;
    float* E2   = ws + OFF_E2;    // 384 KiB
    float* c1W  = ws + OFF_C1;    // 256 B

    // K1: 768 blocks x 512 thr (R15 champion) + c1 epilogue in block 0
    k_rowpipe<<<BQ * VV / 2, 512, 0, stream>>>(
        x, w_in1, b_in1, w_in2, b_in2, w_e1, b_e1, w_e2, b_e2, w_n1, E2, c1W);
    // K2: 512 blocks x 1024 thr, ONE hidden row per block, 32 waves/CU
    k_agg_out<<<BQ * HH, 1024, 0, stream>>>(
        adj, E2, c1W, w_n1, b_n1, w_n2, b_n2, w_out, b_out, out);
}

// Round 18
// 16.025 us; speedup vs baseline: 1.0307x; 1.0307x over previous
//
#include <hip/hip_runtime.h>

// Shapes (compile-time constants from the reference)
#define BQ 4     // B
#define VV 384   // V visible nodes
#define HH 128   // H hidden nodes
#define NN 512   // N = V + H
#define HDIM 64  // HD
#define TD 128   // T*D

typedef float f32x2 __attribute__((ext_vector_type(2)));

// Wave-uniform broadcast: readlane (VALU->SGPR, ~4cyc) instead of __shfl
// (ds_bpermute, ~60+cyc LDS-crossbar latency). Index must be wave-uniform.
__device__ __forceinline__ float BCAST(float v, int l) {
    return __int_as_float(__builtin_amdgcn_readlane(__float_as_int(v), l));
}
__device__ __forceinline__ f32x2 RELU2(f32x2 v) {
    f32x2 r; r.x = fmaxf(v.x, 0.f); r.y = fmaxf(v.y, 0.f); return r;
}

// K1: visible rows only. One row-pair per 512-thread block (8 waves); rows
// packed into f32x2 lanes; wave o covers K-eighth o of every layer.
// 768 blocks x 8 waves = 6144 waves = 24/CU. (R15 champion, 16.08 us)
__global__ __launch_bounds__(512) void k_rowpipe(
    const float* __restrict__ x,       // (B*V,128)
    const float* __restrict__ w_in1,   // (128,64)
    const float* __restrict__ b_in1,   // (64)
    const float* __restrict__ w_in2,   // (64,64)
    const float* __restrict__ b_in2,   // (64)
    const float* __restrict__ w_e1,    // (128,64) ; rows [64:128) = sender half
    const float* __restrict__ b_e1,    // (64)
    const float* __restrict__ w_e2,    // (64,64)
    const float* __restrict__ b_e2,    // (64)
    float* __restrict__ E2)            // (B*V,64) in workspace
{
    __shared__ f32x2 part[4][8][HDIM];   // [layer][eighth][lane] = 16 KB

    const int o    = threadIdx.x >> 6;    // 0..7 : K-eighth
    const int lane = threadIdx.x & 63;
    const int row0 = blockIdx.x * 2;      // rows row0, row0+1 (flat b*V+j)

    const float* xr0 = x + (size_t)row0 * TD;
    const float* xr1 = xr0 + TD;
    // lanes 0-31 carry row0's 16 x-values (dup'd), 32-63 row1's
    const float xv = (lane < 32) ? xr0[16 * o + (lane & 15)]
                                 : xr1[16 * o + (lane & 15)];

    // layer in1: K=128, eighth kg in [16o, 16o+16)
    f32x2 a0 = {0.f, 0.f}, a1 = {0.f, 0.f};
    #pragma unroll
    for (int k = 0; k < 16; k += 2) {
        const int kg = 16 * o + k;
        f32x2 s0; s0.x = BCAST(xv, k);     s0.y = BCAST(xv, 32 + k);
        f32x2 s1; s1.x = BCAST(xv, k + 1); s1.y = BCAST(xv, 33 + k);
        a0 += s0 * w_in1[kg * HDIM + lane];
        a1 += s1 * w_in1[(kg + 1) * HDIM + lane];
    }
    part[0][o][lane] = a0 + a1;
    __syncthreads();
    f32x2 t = ((part[0][0][lane] + part[0][1][lane])
             + (part[0][2][lane] + part[0][3][lane]))
            + ((part[0][4][lane] + part[0][5][lane])
             + (part[0][6][lane] + part[0][7][lane]));
    const f32x2 h1 = RELU2(t + b_in1[lane]);
    const float h1x = h1.x, h1y = h1.y;

    // layer in2: K=64, eighth kg in [8o, 8o+8)
    a0 = (f32x2){0.f, 0.f}; a1 = (f32x2){0.f, 0.f};
    #pragma unroll
    for (int k = 0; k < 8; k += 2) {
        const int kg = 8 * o + k;
        f32x2 s0; s0.x = BCAST(h1x, kg);     s0.y = BCAST(h1y, kg);
        f32x2 s1; s1.x = BCAST(h1x, kg + 1); s1.y = BCAST(h1y, kg + 1);
        a0 += s0 * w_in2[kg * HDIM + lane];
        a1 += s1 * w_in2[(kg + 1) * HDIM + lane];
    }
    part[1][o][lane] = a0 + a1;
    __syncthreads();
    t = ((part[1][0][lane] + part[1][1][lane])
       + (part[1][2][lane] + part[1][3][lane]))
      + ((part[1][4][lane] + part[1][5][lane])
       + (part[1][6][lane] + part[1][7][lane]));
    const f32x2 h2 = RELU2(t + b_in2[lane]);
    const float h2x = h2.x, h2y = h2.y;

    // sender-side edge contribution: bb = h2 @ w_e1[HD:]
    a0 = (f32x2){0.f, 0.f}; a1 = (f32x2){0.f, 0.f};
    #pragma unroll
    for (int k = 0; k < 8; k += 2) {
        const int kg = 8 * o + k;
        f32x2 s0; s0.x = BCAST(h2x, kg);     s0.y = BCAST(h2y, kg);
        f32x2 s1; s1.x = BCAST(h2x, kg + 1); s1.y = BCAST(h2y, kg + 1);
        a0 += s0 * w_e1[(HDIM + kg) * HDIM + lane];
        a1 += s1 * w_e1[(HDIM + kg + 1) * HDIM + lane];
    }
    part[2][o][lane] = a0 + a1;
    __syncthreads();
    t = ((part[2][0][lane] + part[2][1][lane])
       + (part[2][2][lane] + part[2][3][lane]))
      + ((part[2][4][lane] + part[2][5][lane])
       + (part[2][6][lane] + part[2][7][lane]));
    const f32x2 e1 = RELU2(t + b_e1[lane]);
    const float e1x = e1.x, e1y = e1.y;

    // edge layer 2
    a0 = (f32x2){0.f, 0.f}; a1 = (f32x2){0.f, 0.f};
    #pragma unroll
    for (int k = 0; k < 8; k += 2) {
        const int kg = 8 * o + k;
        f32x2 s0; s0.x = BCAST(e1x, kg);     s0.y = BCAST(e1y, kg);
        f32x2 s1; s1.x = BCAST(e1x, kg + 1); s1.y = BCAST(e1y, kg + 1);
        a0 += s0 * w_e2[kg * HDIM + lane];
        a1 += s1 * w_e2[(kg + 1) * HDIM + lane];
    }
    part[3][o][lane] = a0 + a1;
    __syncthreads();
    if (o == 0) {
        t = ((part[3][0][lane] + part[3][1][lane])
           + (part[3][2][lane] + part[3][3][lane]))
          + ((part[3][4][lane] + part[3][5][lane])
           + (part[3][6][lane] + part[3][7][lane]));
        const f32x2 e2v = RELU2(t + b_e2[lane]);
        E2[(size_t)row0 * HDIM + lane]       = e2v.x;
        E2[(size_t)(row0 + 1) * HDIM + lane] = e2v.y;
    }
}

// K2: 256 blocks x 1024 threads (16 waves), 2 hidden rows per block.
// Waves 0-11: visible-sender agg (32 j's each). Waves 12-15: hidden-sender
// adj row-sums; wave 12 also computes the constant e2c vector.
// Tail: two 8-wave groups (one per row), K split 8 ways, LDS reduce.
__global__ __launch_bounds__(1024) void k_agg_out(
    const float* __restrict__ adj,   // (B,N,N)
    const float* __restrict__ E2,    // (B*V,64)
    const float* __restrict__ b_e1, const float* __restrict__ w_e2,
    const float* __restrict__ b_e2,
    const float* __restrict__ w_n1, const float* __restrict__ b_n1,
    const float* __restrict__ w_n2, const float* __restrict__ b_n2,
    const float* __restrict__ w_out, // (64,128)
    const float* __restrict__ b_out, // (128)
    float* __restrict__ out)         // (B,H,128)
{
    const int blk  = blockIdx.x;          // 0..255
    const int b    = blk >> 6;
    const int pair = blk & 63;
    const int wid  = threadIdx.x >> 6;    // 0..15
    const int lane = threadIdx.x & 63;

    const int i0 = VV + pair * 2;
    const float* adjr0 = adj + ((size_t)b * NN + i0) * NN;
    const float* adjr1 = adjr0 + NN;
    const int j0 = wid * 32;              // waves 0-11 visible, 12-15 hidden

    const float adjv = (lane < 32) ? adjr0[j0 + lane] : adjr1[j0 + lane - 32];

    __shared__ float redA[12][2][HDIM];
    __shared__ float hs[4][2];
    __shared__ float e2c[HDIM];

    if (wid < 12) {
        const float* e2b = E2 + ((size_t)b * VV + j0) * HDIM;
        float p0 = 0.f, p1 = 0.f, q0 = 0.f, q1 = 0.f;
        #pragma unroll 8
        for (int jj = 0; jj < 32; jj += 2) {
            const float e0 = e2b[jj * HDIM + lane];
            const float e1 = e2b[(jj + 1) * HDIM + lane];
            p0 = fmaf(BCAST(adjv, jj),      e0, p0);
            q0 = fmaf(BCAST(adjv, 32 + jj), e0, q0);
            p1 = fmaf(BCAST(adjv, jj + 1),  e1, p1);
            q1 = fmaf(BCAST(adjv, 33 + jj), e1, q1);
        }
        redA[wid][0][lane] = p0 + p1;
        redA[wid][1][lane] = q0 + q1;
    } else {
        // hidden senders: row-sum of adj chunk per row via 32-lane tree
        float s = adjv;
        s += __shfl_xor(s, 1, 64);
        s += __shfl_xor(s, 2, 64);
        s += __shfl_xor(s, 4, 64);
        s += __shfl_xor(s, 8, 64);
        s += __shfl_xor(s, 16, 64);
        if (lane == 0)  hs[wid - 12][0] = s;
        if (lane == 32) hs[wid - 12][1] = s;
        if (wid == 12) {
            // constant hidden-sender E2 vector: relu(relu(b_e1)@w_e2 + b_e2)
            const float e1c = fmaxf(b_e1[lane], 0.f);
            float t0 = b_e2[lane], t1 = 0.f;
            #pragma unroll 8
            for (int k = 0; k < HDIM; k += 2) {
                t0 = fmaf(BCAST(e1c, k),     w_e2[k * HDIM + lane],       t0);
                t1 = fmaf(BCAST(e1c, k + 1), w_e2[(k + 1) * HDIM + lane], t1);
            }
            e2c[lane] = fmaxf(t0 + t1, 0.f);
        }
    }
    __syncthreads();

    const int g  = wid >> 3;   // row group (0/1)
    const int w8 = wid & 7;

    const float hsum = hs[0][g] + hs[1][g] + hs[2][g] + hs[3][g];
    float agg = hsum * e2c[lane];
    #pragma unroll
    for (int w = 0; w < 12; ++w) agg += redA[w][g][lane];

    // layer n1: K split 8 ways across the group's waves
    __shared__ float redB[16][HDIM];
    {
        float t0 = 0.f, t1 = 0.f;
        #pragma unroll
        for (int t = 0; t < 8; t += 2) {
            const int k = 8 * w8 + t;
            t0 = fmaf(BCAST(agg, k),     w_n1[k * HDIM + lane],       t0);
            t1 = fmaf(BCAST(agg, k + 1), w_n1[(k + 1) * HDIM + lane], t1);
        }
        redB[wid][lane] = t0 + t1;
    }
    __syncthreads();
    float n1 = b_n1[lane];
    #pragma unroll
    for (int w = 0; w < 8; ++w) n1 += redB[g * 8 + w][lane];
    n1 = fmaxf(n1, 0.f);

    // layer n2
    __shared__ float redC[16][HDIM];
    {
        float t0 = 0.f, t1 = 0.f;
        #pragma unroll
        for (int t = 0; t < 8; t += 2) {
            const int k = 8 * w8 + t;
            t0 = fmaf(BCAST(n1, k),     w_n2[k * HDIM + lane],       t0);
            t1 = fmaf(BCAST(n1, k + 1), w_n2[(k + 1) * HDIM + lane], t1);
        }
        redC[wid][lane] = t0 + t1;
    }
    __syncthreads();
    float n2 = b_n2[lane];
    #pragma unroll
    for (int w = 0; w < 8; ++w) n2 += redC[g * 8 + w][lane];
    n2 = fmaxf(n2, 0.f);

    // out layer: 128 outputs, K split 8 ways
    __shared__ float redD[16][TD];
    {
        float o0 = 0.f, o1 = 0.f;
        #pragma unroll
        for (int t = 0; t < 8; ++t) {
            const int k = 8 * w8 + t;
            const float v = BCAST(n2, k);
            o0 = fmaf(v, w_out[k * TD + lane],      o0);
            o1 = fmaf(v, w_out[k * TD + 64 + lane], o1);
        }
        redD[wid][lane]      = o0;
        redD[wid][64 + lane] = o1;
    }
    __syncthreads();

    if (w8 < 2) {
        const int col = w8 * 64 + lane;
        float o = b_out[col];
        #pragma unroll
        for (int w = 0; w < 8; ++w) o += redD[g * 8 + w][col];
        const int orow = b * HH + pair * 2 + g;
        out[(size_t)orow * TD + col] = o;
    }
}

extern "C" void kernel_launch(void* const* d_in, const int* in_sizes, int n_in,
                              void* d_out, int out_size, void* d_ws, size_t ws_size,
                              hipStream_t stream) {
    const float* x     = (const float*)d_in[0];
    const float* adj   = (const float*)d_in[1];
    const float* w_in1 = (const float*)d_in[2];
    const float* b_in1 = (const float*)d_in[3];
    const float* w_in2 = (const float*)d_in[4];
    const float* b_in2 = (const float*)d_in[5];
    const float* w_e1  = (const float*)d_in[6];
    const float* b_e1  = (const float*)d_in[7];
    const float* w_e2  = (const float*)d_in[8];
    const float* b_e2  = (const float*)d_in[9];
    const float* w_n1  = (const float*)d_in[10];
    const float* b_n1  = (const float*)d_in[11];
    const float* w_n2  = (const float*)d_in[12];
    const float* b_n2  = (const float*)d_in[13];
    const float* w_out = (const float*)d_in[14];
    const float* b_out = (const float*)d_in[15];
    float* out = (float*)d_out;
    float* E2  = (float*)d_ws;   // B*V*64 floats = 384 KiB

    // K1: 768 blocks x 512 thr (1 row-pair, 8 K-eighth waves) = 24 waves/CU
    k_rowpipe<<<BQ * VV / 2, 512, 0, stream>>>(
        x, w_in1, b_in1, w_in2, b_in2, w_e1, b_e1, w_e2, b_e2, E2);
    // K2: 256 blocks x 1024 threads, 2 hidden rows per block
    k_agg_out<<<BQ * HH / 2, 1024, 0, stream>>>(
        adj, E2, b_e1, w_e2, b_e2, w_n1, b_n1, w_n2, b_n2, w_out, b_out, out);
}

// Round 19
// 16.005 us; speedup vs baseline: 1.0320x; 1.0012x over previous
//
#include <hip/hip_runtime.h>

// Shapes (compile-time constants from the reference)
#define BQ 4     // B
#define VV 384   // V visible nodes
#define HH 128   // H hidden nodes
#define NN 512   // N = V + H
#define HDIM 64  // HD
#define TD 128   // T*D

typedef float f32x2 __attribute__((ext_vector_type(2)));

// Wave-uniform broadcast: readlane (VALU->SGPR, ~4cyc) instead of __shfl
// (ds_bpermute, ~60+cyc LDS-crossbar latency). Index must be wave-uniform.
__device__ __forceinline__ float BCAST(float v, int l) {
    return __int_as_float(__builtin_amdgcn_readlane(__float_as_int(v), l));
}
__device__ __forceinline__ f32x2 RELU2(f32x2 v) {
    f32x2 r; r.x = fmaxf(v.x, 0.f); r.y = fmaxf(v.y, 0.f); return r;
}
// round-to-nearest-even f32 -> bf16 bits (values are finite, post-relu)
__device__ __forceinline__ unsigned BF16(float f) {
    const unsigned u = __float_as_uint(f);
    return (u + 0x7fffu + ((u >> 16) & 1u)) >> 16;
}

// K1: visible rows only. One row-pair per 512-thread block (8 waves); rows
// packed into f32x2 lanes; wave o covers K-eighth o of every layer.
// 768 blocks x 8 waves = 6144 waves = 24/CU. (R15 champion geometry.)
// Epilogue packs the 2 rows (even j, odd j) as bf16 into one u32 per lane.
__global__ __launch_bounds__(512) void k_rowpipe(
    const float* __restrict__ x,       // (B*V,128)
    const float* __restrict__ w_in1,   // (128,64)
    const float* __restrict__ b_in1,   // (64)
    const float* __restrict__ w_in2,   // (64,64)
    const float* __restrict__ b_in2,   // (64)
    const float* __restrict__ w_e1,    // (128,64) ; rows [64:128) = sender half
    const float* __restrict__ b_e1,    // (64)
    const float* __restrict__ w_e2,    // (64,64)
    const float* __restrict__ b_e2,    // (64)
    unsigned* __restrict__ E2p)        // (B*V/2, 64) u32: bf16 j-pairs
{
    __shared__ f32x2 part[4][8][HDIM];   // [layer][eighth][lane] = 16 KB

    const int o    = threadIdx.x >> 6;    // 0..7 : K-eighth
    const int lane = threadIdx.x & 63;
    const int row0 = blockIdx.x * 2;      // rows row0, row0+1 (flat b*V+j)

    const float* xr0 = x + (size_t)row0 * TD;
    const float* xr1 = xr0 + TD;
    // lanes 0-31 carry row0's 16 x-values (dup'd), 32-63 row1's
    const float xv = (lane < 32) ? xr0[16 * o + (lane & 15)]
                                 : xr1[16 * o + (lane & 15)];

    // layer in1: K=128, eighth kg in [16o, 16o+16)
    f32x2 a0 = {0.f, 0.f}, a1 = {0.f, 0.f};
    #pragma unroll
    for (int k = 0; k < 16; k += 2) {
        const int kg = 16 * o + k;
        f32x2 s0; s0.x = BCAST(xv, k);     s0.y = BCAST(xv, 32 + k);
        f32x2 s1; s1.x = BCAST(xv, k + 1); s1.y = BCAST(xv, 33 + k);
        a0 += s0 * w_in1[kg * HDIM + lane];
        a1 += s1 * w_in1[(kg + 1) * HDIM + lane];
    }
    part[0][o][lane] = a0 + a1;
    __syncthreads();
    f32x2 t = ((part[0][0][lane] + part[0][1][lane])
             + (part[0][2][lane] + part[0][3][lane]))
            + ((part[0][4][lane] + part[0][5][lane])
             + (part[0][6][lane] + part[0][7][lane]));
    const f32x2 h1 = RELU2(t + b_in1[lane]);
    const float h1x = h1.x, h1y = h1.y;

    // layer in2: K=64, eighth kg in [8o, 8o+8)
    a0 = (f32x2){0.f, 0.f}; a1 = (f32x2){0.f, 0.f};
    #pragma unroll
    for (int k = 0; k < 8; k += 2) {
        const int kg = 8 * o + k;
        f32x2 s0; s0.x = BCAST(h1x, kg);     s0.y = BCAST(h1y, kg);
        f32x2 s1; s1.x = BCAST(h1x, kg + 1); s1.y = BCAST(h1y, kg + 1);
        a0 += s0 * w_in2[kg * HDIM + lane];
        a1 += s1 * w_in2[(kg + 1) * HDIM + lane];
    }
    part[1][o][lane] = a0 + a1;
    __syncthreads();
    t = ((part[1][0][lane] + part[1][1][lane])
       + (part[1][2][lane] + part[1][3][lane]))
      + ((part[1][4][lane] + part[1][5][lane])
       + (part[1][6][lane] + part[1][7][lane]));
    const f32x2 h2 = RELU2(t + b_in2[lane]);
    const float h2x = h2.x, h2y = h2.y;

    // sender-side edge contribution: bb = h2 @ w_e1[HD:]
    a0 = (f32x2){0.f, 0.f}; a1 = (f32x2){0.f, 0.f};
    #pragma unroll
    for (int k = 0; k < 8; k += 2) {
        const int kg = 8 * o + k;
        f32x2 s0; s0.x = BCAST(h2x, kg);     s0.y = BCAST(h2y, kg);
        f32x2 s1; s1.x = BCAST(h2x, kg + 1); s1.y = BCAST(h2y, kg + 1);
        a0 += s0 * w_e1[(HDIM + kg) * HDIM + lane];
        a1 += s1 * w_e1[(HDIM + kg + 1) * HDIM + lane];
    }
    part[2][o][lane] = a0 + a1;
    __syncthreads();
    t = ((part[2][0][lane] + part[2][1][lane])
       + (part[2][2][lane] + part[2][3][lane]))
      + ((part[2][4][lane] + part[2][5][lane])
       + (part[2][6][lane] + part[2][7][lane]));
    const f32x2 e1 = RELU2(t + b_e1[lane]);
    const float e1x = e1.x, e1y = e1.y;

    // edge layer 2
    a0 = (f32x2){0.f, 0.f}; a1 = (f32x2){0.f, 0.f};
    #pragma unroll
    for (int k = 0; k < 8; k += 2) {
        const int kg = 8 * o + k;
        f32x2 s0; s0.x = BCAST(e1x, kg);     s0.y = BCAST(e1y, kg);
        f32x2 s1; s1.x = BCAST(e1x, kg + 1); s1.y = BCAST(e1y, kg + 1);
        a0 += s0 * w_e2[kg * HDIM + lane];
        a1 += s1 * w_e2[(kg + 1) * HDIM + lane];
    }
    part[3][o][lane] = a0 + a1;
    __syncthreads();
    if (o == 0) {
        t = ((part[3][0][lane] + part[3][1][lane])
           + (part[3][2][lane] + part[3][3][lane]))
          + ((part[3][4][lane] + part[3][5][lane])
           + (part[3][6][lane] + part[3][7][lane]));
        const f32x2 e2v = RELU2(t + b_e2[lane]);
        // pack (even j = x, odd j = y) as bf16 pair
        E2p[(size_t)blockIdx.x * HDIM + lane] = (BF16(e2v.y) << 16) | BF16(e2v.x);
    }
}

// K2: 256 blocks x 1024 threads (16 waves), 2 hidden rows per block.
// Waves 0-11: visible-sender agg — E2 read as bf16 j-PAIRS (16 u32 loads
// per wave instead of 32 f32 loads; fp32 accumulate). Waves 12-15: hidden
// row-sums + e2c. Tail: champion split-8 form, unchanged.
__global__ __launch_bounds__(1024) void k_agg_out(
    const float* __restrict__ adj,      // (B,N,N)
    const unsigned* __restrict__ E2p,   // (B*V/2, 64) bf16 pairs
    const float* __restrict__ b_e1, const float* __restrict__ w_e2,
    const float* __restrict__ b_e2,
    const float* __restrict__ w_n1, const float* __restrict__ b_n1,
    const float* __restrict__ w_n2, const float* __restrict__ b_n2,
    const float* __restrict__ w_out, // (64,128)
    const float* __restrict__ b_out, // (128)
    float* __restrict__ out)         // (B,H,128)
{
    const int blk  = blockIdx.x;          // 0..255
    const int b    = blk >> 6;
    const int pair = blk & 63;
    const int wid  = threadIdx.x >> 6;    // 0..15
    const int lane = threadIdx.x & 63;

    const int i0 = VV + pair * 2;
    const float* adjr0 = adj + ((size_t)b * NN + i0) * NN;
    const float* adjr1 = adjr0 + NN;
    const int j0 = wid * 32;              // waves 0-11 visible, 12-15 hidden

    const float adjv = (lane < 32) ? adjr0[j0 + lane] : adjr1[j0 + lane - 32];

    __shared__ float redA[12][2][HDIM];
    __shared__ float hs[4][2];
    __shared__ float e2c[HDIM];

    if (wid < 12) {
        // 16 bf16-pair loads cover j0..j0+31
        const unsigned* e2p = E2p + ((size_t)b * (VV / 2) + (j0 >> 1)) * HDIM;
        float p0 = 0.f, p1 = 0.f, q0 = 0.f, q1 = 0.f;
        #pragma unroll 8
        for (int t2 = 0; t2 < 16; ++t2) {
            const unsigned w = e2p[t2 * HDIM + lane];
            const float e0 = __uint_as_float(w << 16);           // j = j0+2*t2
            const float e1 = __uint_as_float(w & 0xffff0000u);   // j = j0+2*t2+1
            p0 = fmaf(BCAST(adjv, 2 * t2),      e0, p0);
            q0 = fmaf(BCAST(adjv, 32 + 2 * t2), e0, q0);
            p1 = fmaf(BCAST(adjv, 2 * t2 + 1),  e1, p1);
            q1 = fmaf(BCAST(adjv, 33 + 2 * t2), e1, q1);
        }
        redA[wid][0][lane] = p0 + p1;
        redA[wid][1][lane] = q0 + q1;
    } else {
        // hidden senders: row-sum of adj chunk per row via 32-lane tree
        float s = adjv;
        s += __shfl_xor(s, 1, 64);
        s += __shfl_xor(s, 2, 64);
        s += __shfl_xor(s, 4, 64);
        s += __shfl_xor(s, 8, 64);
        s += __shfl_xor(s, 16, 64);
        if (lane == 0)  hs[wid - 12][0] = s;
        if (lane == 32) hs[wid - 12][1] = s;
        if (wid == 12) {
            // constant hidden-sender E2 vector: relu(relu(b_e1)@w_e2 + b_e2)
            const float e1c = fmaxf(b_e1[lane], 0.f);
            float t0 = b_e2[lane], t1 = 0.f;
            #pragma unroll 8
            for (int k = 0; k < HDIM; k += 2) {
                t0 = fmaf(BCAST(e1c, k),     w_e2[k * HDIM + lane],       t0);
                t1 = fmaf(BCAST(e1c, k + 1), w_e2[(k + 1) * HDIM + lane], t1);
            }
            e2c[lane] = fmaxf(t0 + t1, 0.f);
        }
    }
    __syncthreads();

    const int g  = wid >> 3;   // row group (0/1)
    const int w8 = wid & 7;

    const float hsum = hs[0][g] + hs[1][g] + hs[2][g] + hs[3][g];
    float agg = hsum * e2c[lane];
    #pragma unroll
    for (int w = 0; w < 12; ++w) agg += redA[w][g][lane];

    // layer n1: K split 8 ways across the group's waves
    __shared__ float redB[16][HDIM];
    {
        float t0 = 0.f, t1 = 0.f;
        #pragma unroll
        for (int t = 0; t < 8; t += 2) {
            const int k = 8 * w8 + t;
            t0 = fmaf(BCAST(agg, k),     w_n1[k * HDIM + lane],       t0);
            t1 = fmaf(BCAST(agg, k + 1), w_n1[(k + 1) * HDIM + lane], t1);
        }
        redB[wid][lane] = t0 + t1;
    }
    __syncthreads();
    float n1 = b_n1[lane];
    #pragma unroll
    for (int w = 0; w < 8; ++w) n1 += redB[g * 8 + w][lane];
    n1 = fmaxf(n1, 0.f);

    // layer n2
    __shared__ float redC[16][HDIM];
    {
        float t0 = 0.f, t1 = 0.f;
        #pragma unroll
        for (int t = 0; t < 8; t += 2) {
            const int k = 8 * w8 + t;
            t0 = fmaf(BCAST(n1, k),     w_n2[k * HDIM + lane],       t0);
            t1 = fmaf(BCAST(n1, k + 1), w_n2[(k + 1) * HDIM + lane], t1);
        }
        redC[wid][lane] = t0 + t1;
    }
    __syncthreads();
    float n2 = b_n2[lane];
    #pragma unroll
    for (int w = 0; w < 8; ++w) n2 += redC[g * 8 + w][lane];
    n2 = fmaxf(n2, 0.f);

    // out layer: 128 outputs, K split 8 ways
    __shared__ float redD[16][TD];
    {
        float o0 = 0.f, o1 = 0.f;
        #pragma unroll
        for (int t = 0; t < 8; ++t) {
            const int k = 8 * w8 + t;
            const float v = BCAST(n2, k);
            o0 = fmaf(v, w_out[k * TD + lane],      o0);
            o1 = fmaf(v, w_out[k * TD + 64 + lane], o1);
        }
        redD[wid][lane]      = o0;
        redD[wid][64 + lane] = o1;
    }
    __syncthreads();

    if (w8 < 2) {
        const int col = w8 * 64 + lane;
        float o = b_out[col];
        #pragma unroll
        for (int w = 0; w < 8; ++w) o += redD[g * 8 + w][col];
        const int orow = b * HH + pair * 2 + g;
        out[(size_t)orow * TD + col] = o;
    }
}

extern "C" void kernel_launch(void* const* d_in, const int* in_sizes, int n_in,
                              void* d_out, int out_size, void* d_ws, size_t ws_size,
                              hipStream_t stream) {
    const float* x     = (const float*)d_in[0];
    const float* adj   = (const float*)d_in[1];
    const float* w_in1 = (const float*)d_in[2];
    const float* b_in1 = (const float*)d_in[3];
    const float* w_in2 = (const float*)d_in[4];
    const float* b_in2 = (const float*)d_in[5];
    const float* w_e1  = (const float*)d_in[6];
    const float* b_e1  = (const float*)d_in[7];
    const float* w_e2  = (const float*)d_in[8];
    const float* b_e2  = (const float*)d_in[9];
    const float* w_n1  = (const float*)d_in[10];
    const float* b_n1  = (const float*)d_in[11];
    const float* w_n2  = (const float*)d_in[12];
    const float* b_n2  = (const float*)d_in[13];
    const float* w_out = (const float*)d_in[14];
    const float* b_out = (const float*)d_in[15];
    float* out = (float*)d_out;
    unsigned* E2p = (unsigned*)d_ws;   // (B*V/2)*64 u32 = 192 KiB

    // K1: 768 blocks x 512 thr (1 row-pair, 8 K-eighth waves) = 24 waves/CU
    k_rowpipe<<<BQ * VV / 2, 512, 0, stream>>>(
        x, w_in1, b_in1, w_in2, b_in2, w_e1, b_e1, w_e2, b_e2, E2p);
    // K2: 256 blocks x 1024 threads, 2 hidden rows per block
    k_agg_out<<<BQ * HH / 2, 1024, 0, stream>>>(
        adj, E2p, b_e1, w_e2, b_e2, w_n1, b_n1, w_n2, b_n2, w_out, b_out, out);
}